// Round 1
// baseline (28.179 us; speedup 1.0000x reference)
//
#include <hip/hip_runtime.h>
#include <hip/hip_bf16.h>

#define B_ROWS 131072
#define L_LEN 64
#define N_TOPICS 81

// One 64-lane wave per row.
// lane j: load hard_label[row*64+j] (coalesced), if (j >= sent_idx[row] && lab >= 0)
// gather P[row*81+lab]; wave-max-reduce; lane 0 writes -max (max floored at 0 by init).
__global__ __launch_bounds__(256) void rangeshrink_max_kernel(
    const float* __restrict__ P,
    const int* __restrict__ hard_label,
    const int* __restrict__ sent_idx,
    float* __restrict__ out,
    int nrows)
{
    const int wave_in_block = threadIdx.x >> 6;   // 4 waves per block
    const int lane = threadIdx.x & 63;
    const int row = blockIdx.x * 4 + wave_in_block;
    if (row >= nrows) return;

    const int si = sent_idx[row];                 // broadcast read (same addr per wave)
    const int lab = hard_label[(size_t)row * L_LEN + lane];

    float v = 0.0f;
    if (lane >= si && lab >= 0) {
        v = P[(size_t)row * N_TOPICS + lab];
    }

    // 64-lane butterfly max reduction
    #pragma unroll
    for (int off = 32; off > 0; off >>= 1) {
        v = fmaxf(v, __shfl_xor(v, off, 64));
    }

    if (lane == 0) {
        out[row] = -v;
    }
}

extern "C" void kernel_launch(void* const* d_in, const int* in_sizes, int n_in,
                              void* d_out, int out_size, void* d_ws, size_t ws_size,
                              hipStream_t stream) {
    const float* P          = (const float*)d_in[0];
    const int*   hard_label = (const int*)d_in[1];
    const int*   sent_idx   = (const int*)d_in[2];
    float*       out        = (float*)d_out;

    const int nrows = out_size;                    // 131072
    const int rows_per_block = 4;                  // 256 threads = 4 waves
    const int grid = (nrows + rows_per_block - 1) / rows_per_block;

    rangeshrink_max_kernel<<<grid, 256, 0, stream>>>(P, hard_label, sent_idx, out, nrows);
}

// Round 2
// 17.334 us; speedup vs baseline: 1.6257x; 1.6257x over previous
//
#include <hip/hip_runtime.h>
#include <hip/hip_bf16.h>

#define L_LEN 64
#define N_TOPICS 81

// One 64-lane wave handles 8 rows.
// Lanes are split into 4 groups of 16; group g owns rows (base+g) and (base+4+g).
// Each lane loads int4 of labels per row (coalesced 16B), does 4 clamped gathers
// per row (branchless, all loads in flight), then a 16-lane butterfly max.
__global__ __launch_bounds__(256) void rangeshrink_max_kernel(
    const float* __restrict__ P,
    const int* __restrict__ hard_label,
    const int* __restrict__ sent_idx,
    float* __restrict__ out,
    int nrows)
{
    const int wave = threadIdx.x >> 6;        // 4 waves per block
    const int lane = threadIdx.x & 63;
    const int group = lane >> 4;              // 0..3
    const int lig   = lane & 15;              // 0..15

    const int base = (blockIdx.x * 4 + wave) * 8;
    const int rowA = base + group;
    const int rowB = base + 4 + group;
    if (rowA >= nrows) return;
    const bool hasB = (rowB < nrows);

    const int4* __restrict__ hl4 = (const int4*)hard_label;   // 16 int4 per row

    // Independent label loads (2 x dwordx4 in flight)
    int4 la = hl4[(size_t)rowA * 16 + lig];
    int4 lb = hasB ? hl4[(size_t)rowB * 16 + lig] : make_int4(-1, -1, -1, -1);

    const int siA = sent_idx[rowA];
    const int siB = hasB ? sent_idx[rowB] : 0;

    const float* __restrict__ Pa = P + (size_t)rowA * N_TOPICS;
    const float* __restrict__ Pb = P + (size_t)rowB * N_TOPICS;

    const int j0 = lig * 4;                   // position of la.x within the row

    // Branchless gathers: clamp invalid label to 0, select 0.0f afterwards.
    int labsA[4] = { la.x, la.y, la.z, la.w };
    int labsB[4] = { lb.x, lb.y, lb.z, lb.w };

    float va = 0.0f, vb = 0.0f;
    float ga[4], gb[4];
    bool  ca[4], cb[4];
    #pragma unroll
    for (int k = 0; k < 4; ++k) {
        ca[k] = (j0 + k >= siA) && (labsA[k] >= 0);
        cb[k] = (j0 + k >= siB) && (labsB[k] >= 0) && hasB;
        int ia = ca[k] ? labsA[k] : 0;
        int ib = cb[k] ? labsB[k] : 0;
        ga[k] = Pa[ia];                        // all 8 loads issue unconditionally
        gb[k] = Pb[ib];
    }
    #pragma unroll
    for (int k = 0; k < 4; ++k) {
        va = fmaxf(va, ca[k] ? ga[k] : 0.0f);
        vb = fmaxf(vb, cb[k] ? gb[k] : 0.0f);
    }

    // 16-lane butterfly max (xor offsets < 16 stay inside the group)
    #pragma unroll
    for (int off = 1; off < 16; off <<= 1) {
        va = fmaxf(va, __shfl_xor(va, off, 64));
        vb = fmaxf(vb, __shfl_xor(vb, off, 64));
    }

    if (lig == 0) {
        out[rowA] = -va;
        if (hasB) out[rowB] = -vb;
    }
}

extern "C" void kernel_launch(void* const* d_in, const int* in_sizes, int n_in,
                              void* d_out, int out_size, void* d_ws, size_t ws_size,
                              hipStream_t stream) {
    const float* P          = (const float*)d_in[0];
    const int*   hard_label = (const int*)d_in[1];
    const int*   sent_idx   = (const int*)d_in[2];
    float*       out        = (float*)d_out;

    const int nrows = out_size;                     // 131072
    const int rows_per_block = 32;                  // 4 waves * 8 rows
    const int grid = (nrows + rows_per_block - 1) / rows_per_block;

    rangeshrink_max_kernel<<<grid, 256, 0, stream>>>(P, hard_label, sent_idx, out, nrows);
}

// Round 3
// 17.131 us; speedup vs baseline: 1.6449x; 1.0119x over previous
//
#include <hip/hip_runtime.h>
#include <hip/hip_bf16.h>

#define L_LEN 64
#define N_TOPICS 81
#define ROW_STRIDE 84          // LDS floats per row; 84 % 32 = 20 -> 8-lane group reads hit distinct banks
#define ROWS_PER_WAVE 8
#define WAVES_PER_BLOCK 4
#define ROWS_PER_BLOCK 32      // 4 waves * 8 rows

// Strategy: membership table in LDS + fully linear P reads.
//  - Each wave owns 8 rows; 8 lanes per row.
//  - Phase 0: issue 11 coalesced dword loads of P per lane (independent of labels).
//  - Phase 1: load 8 labels/lane (2x int4, coalesced), zero this wave's LDS region,
//             scatter member[row][lab] = 1.0f for valid (pos >= sent_idx, lab >= 0).
//  - Phase 2: v = max over t of member[row][lig+8t] * P[row][lig+8t]  (P >= 0, so
//             multiply == masked select, and init 0 gives the max(0, .) floor).
//  - 3-stage 8-lane butterfly; lane 0 of each group writes -v.
// All LDS traffic is wave-private (no __syncthreads needed; DS ops are in-order per wave).
__global__ __launch_bounds__(256) void rangeshrink_max_kernel(
    const float* __restrict__ P,
    const int* __restrict__ hard_label,
    const int* __restrict__ sent_idx,
    float* __restrict__ out,
    int nrows)
{
    __shared__ float member[ROWS_PER_BLOCK * ROW_STRIDE];   // 32*84*4 = 10752 B

    const int wave = threadIdx.x >> 6;
    const int lane = threadIdx.x & 63;
    const int g    = lane >> 3;          // row within wave (0..7)
    const int lig  = lane & 7;           // lane in group (0..7)

    const int localRow = wave * ROWS_PER_WAVE + g;
    const int row = blockIdx.x * ROWS_PER_BLOCK + localRow;
    if (row >= nrows) return;            // grid divides exactly in practice

    // ---- Phase 0: P loads early, coalesced dwords (independent of labels) ----
    const float* __restrict__ Prow = P + (size_t)row * N_TOPICS;
    float pv[11];
    #pragma unroll
    for (int t = 0; t < 11; ++t) {
        const int idx = lig + 8 * t;
        pv[t] = (idx <= 80) ? Prow[idx] : 0.0f;
    }

    // ---- Phase 1a: labels (coalesced 2x int4 per lane) + sent_idx ----
    const int4* __restrict__ hl4 = (const int4*)hard_label;
    const int4 la = hl4[(size_t)row * 16 + lig * 2];
    const int4 lb = hl4[(size_t)row * 16 + lig * 2 + 1];
    const int si = sent_idx[row];

    // ---- Phase 1b: zero this wave's member region (672 dwords, stride-64 -> conflict-free) ----
    float* const mwave = member + (wave * ROWS_PER_WAVE) * ROW_STRIDE;
    #pragma unroll
    for (int t = 0; t < 11; ++t) {
        const int d = lane + 64 * t;
        if (d < ROWS_PER_WAVE * ROW_STRIDE) mwave[d] = 0.0f;
    }
    __builtin_amdgcn_wave_barrier();     // pin ordering: zero before scatter

    // ---- Phase 1c: scatter membership ----
    float* const srow = member + localRow * ROW_STRIDE;
    const int labs[8] = { la.x, la.y, la.z, la.w, lb.x, lb.y, lb.z, lb.w };
    #pragma unroll
    for (int k = 0; k < 8; ++k) {
        const int j = lig * 8 + k;       // position of this label in the row
        if (j >= si && labs[k] >= 0) srow[labs[k]] = 1.0f;
    }
    __builtin_amdgcn_wave_barrier();     // pin ordering: scatter before reads

    // ---- Phase 2: masked max via member * P ----
    const float* const mrow = member + localRow * ROW_STRIDE;
    float v = 0.0f;
    #pragma unroll
    for (int t = 0; t < 11; ++t) {
        const int idx = lig + 8 * t;
        if (idx <= 80) v = fmaxf(v, mrow[idx] * pv[t]);
    }

    // ---- 8-lane butterfly max ----
    #pragma unroll
    for (int off = 1; off < 8; off <<= 1) {
        v = fmaxf(v, __shfl_xor(v, off, 64));
    }

    if (lig == 0) out[row] = -v;
}

extern "C" void kernel_launch(void* const* d_in, const int* in_sizes, int n_in,
                              void* d_out, int out_size, void* d_ws, size_t ws_size,
                              hipStream_t stream) {
    const float* P          = (const float*)d_in[0];
    const int*   hard_label = (const int*)d_in[1];
    const int*   sent_idx   = (const int*)d_in[2];
    float*       out        = (float*)d_out;

    const int nrows = out_size;                              // 131072
    const int grid = (nrows + ROWS_PER_BLOCK - 1) / ROWS_PER_BLOCK;   // 4096

    rangeshrink_max_kernel<<<grid, 256, 0, stream>>>(P, hard_label, sent_idx, out, nrows);
}